// Round 1
// baseline (317.171 us; speedup 1.0000x reference)
//
#include <hip/hip_runtime.h>
#include <hip/hip_bf16.h>

// Problem constants (from reference)
#define B_   8
#define S_   2048
#define D_   1280
#define OUT_ 1280
#define K_   (2 * D_)     // 2560
#define M_   (B_ * S_)    // 16384

#define BM 128
#define BN 128
#define BK 32
#define LDK 40            // padded LDS leading dim (bf16 elems): +8 pad -> conflict-free b128 reads

typedef __bf16 bf16_t;
typedef bf16_t bf16x8 __attribute__((ext_vector_type(8)));
typedef float  f32x4  __attribute__((ext_vector_type(4)));

// ---------------------------------------------------------------------------
// Kernel 1: per-batch valid-length from mask. Handles both storage formats:
//  - bool/byte layout: element i at byte i
//  - int32 layout:     element i at word i
// Discriminator: mask[0][1] is always 1 (lengths >= S/4 = 512). If the buffer
// is int32, byte #1 is the 2nd byte of value 1 -> 0. If bytes, byte #1 -> 1.
// ---------------------------------------------------------------------------
__global__ void lengths_kernel(const unsigned char* __restrict__ mask,
                               int* __restrict__ len) {
    const int b = blockIdx.x;
    const bool bytefmt = (mask[1] != 0);
    int cnt = 0;
    if (bytefmt) {
        for (int s = threadIdx.x; s < S_; s += blockDim.x)
            cnt += (mask[(size_t)b * S_ + s] != 0) ? 1 : 0;
    } else {
        const int* mi = (const int*)mask;
        for (int s = threadIdx.x; s < S_; s += blockDim.x)
            cnt += (mi[(size_t)b * S_ + s] != 0) ? 1 : 0;
    }
    // wave reduce (wave64)
    #pragma unroll
    for (int off = 32; off > 0; off >>= 1) cnt += __shfl_down(cnt, off);
    __shared__ int wsum[4];
    const int wid = threadIdx.x >> 6;
    if ((threadIdx.x & 63) == 0) wsum[wid] = cnt;
    __syncthreads();
    if (threadIdx.x == 0) len[b] = wsum[0] + wsum[1] + wsum[2] + wsum[3];
}

// ---------------------------------------------------------------------------
// Kernel 2: fused masked-reverse + concat + GEMM (+bias).
// out[m][o] = sum_k A[m][k] * W[o][k] + bias[o]
//   A[m][k] = forward[b][s][k]            (k <  D)
//           = reverse[b][s'][k-D]         (k >= D), s' = (s<n) ? n-1-s : s
// 128x128 tile, BK=32, 4 waves (2x2 of 64x64), mfma_f32_16x16x32_bf16.
// Reg-staged f32->bf16 into padded LDS.
// ---------------------------------------------------------------------------
__device__ inline bf16x8 cvt8(float4 x, float4 y) {
    bf16x8 r;
    r[0] = (bf16_t)x.x; r[1] = (bf16_t)x.y; r[2] = (bf16_t)x.z; r[3] = (bf16_t)x.w;
    r[4] = (bf16_t)y.x; r[5] = (bf16_t)y.y; r[6] = (bf16_t)y.z; r[7] = (bf16_t)y.w;
    return r;
}

__global__ __launch_bounds__(256) void profam_gemm_kernel(
    const float* __restrict__ fwd, const float* __restrict__ rev,
    const float* __restrict__ W,   const float* __restrict__ bias,
    const int* __restrict__ len,   float* __restrict__ out) {

    __shared__ __align__(16) bf16_t lds_a[BM][LDK];
    __shared__ __align__(16) bf16_t lds_b[BN][LDK];

    const int ct = blockIdx.x;            // 0..9   (N tiles)  fastest -> share A panel
    const int rt = blockIdx.y;            // 0..127 (M tiles)
    const int m0 = rt * BM;
    const int n0 = ct * BN;
    const int t  = threadIdx.x;
    const int l  = t & 63;
    const int w  = t >> 6;
    const int wr = w >> 1, wc = w & 1;    // wave -> 64x64 quadrant

    const int b = m0 >> 11;               // S_ = 2048; tile is within one batch
    const int n = len[b];

    // staging: thread t handles tile-row (t>>1), 16-col group ((t&1)*16)
    const int sr = t >> 1;
    const int cg = (t & 1) * 16;
    const int s  = (m0 + sr) & (S_ - 1);
    const int ss = (s < n) ? (n - 1 - s) : s;
    const float* pf = fwd + (size_t)(b * S_ + s)  * D_ + cg;
    const float* pr = rev + (size_t)(b * S_ + ss) * D_ + cg;
    const float* pw = W   + (size_t)(n0 + sr) * K_ + cg;

    f32x4 acc[4][4] = {};

    const int lrow = l & 15;
    const int kc   = (l >> 4) * 8;        // k-chunk within BK for this lane

    for (int kt = 0; kt < K_ / BK; ++kt) {
        const int k0 = kt * BK;
        const float* pa = (k0 < D_) ? (pf + k0) : (pr + (k0 - D_));
        const float* pb = pw + k0;

        float4 a0 = *(const float4*)(pa + 0);
        float4 a1 = *(const float4*)(pa + 4);
        float4 a2 = *(const float4*)(pa + 8);
        float4 a3 = *(const float4*)(pa + 12);
        float4 b0 = *(const float4*)(pb + 0);
        float4 b1 = *(const float4*)(pb + 4);
        float4 b2 = *(const float4*)(pb + 8);
        float4 b3 = *(const float4*)(pb + 12);

        *(bf16x8*)&lds_a[sr][cg + 0] = cvt8(a0, a1);
        *(bf16x8*)&lds_a[sr][cg + 8] = cvt8(a2, a3);
        *(bf16x8*)&lds_b[sr][cg + 0] = cvt8(b0, b1);
        *(bf16x8*)&lds_b[sr][cg + 8] = cvt8(b2, b3);

        __syncthreads();

        bf16x8 af[4], bf[4];
        #pragma unroll
        for (int i = 0; i < 4; ++i)
            af[i] = *(const bf16x8*)&lds_a[wr * 64 + i * 16 + lrow][kc];
        #pragma unroll
        for (int j = 0; j < 4; ++j)
            bf[j] = *(const bf16x8*)&lds_b[wc * 64 + j * 16 + lrow][kc];

        #pragma unroll
        for (int i = 0; i < 4; ++i)
            #pragma unroll
            for (int j = 0; j < 4; ++j)
                acc[i][j] = __builtin_amdgcn_mfma_f32_16x16x32_bf16(
                    af[i], bf[j], acc[i][j], 0, 0, 0);

        __syncthreads();
    }

    // epilogue: C/D layout col=lane&15, row=(lane>>4)*4+v  [verified m89]
    #pragma unroll
    for (int j = 0; j < 4; ++j) {
        const int col = n0 + wc * 64 + j * 16 + lrow;
        const float bj = bias[col];
        #pragma unroll
        for (int i = 0; i < 4; ++i) {
            const int row0 = m0 + wr * 64 + i * 16 + (l >> 4) * 4;
            #pragma unroll
            for (int v = 0; v < 4; ++v)
                out[(size_t)(row0 + v) * OUT_ + col] = acc[i][j][v] + bj;
        }
    }
}

extern "C" void kernel_launch(void* const* d_in, const int* in_sizes, int n_in,
                              void* d_out, int out_size, void* d_ws, size_t ws_size,
                              hipStream_t stream) {
    const float* fwd  = (const float*)d_in[0];
    const float* rev  = (const float*)d_in[1];
    const unsigned char* mask = (const unsigned char*)d_in[2];
    const float* W    = (const float*)d_in[3];
    const float* bias = (const float*)d_in[4];
    float* out = (float*)d_out;
    int* len = (int*)d_ws;   // 8 ints of scratch

    lengths_kernel<<<dim3(B_), dim3(256), 0, stream>>>(mask, len);

    dim3 grid(OUT_ / BN, M_ / BM);   // (10, 128); x fastest -> neighbors share A panel
    profam_gemm_kernel<<<grid, dim3(256), 0, stream>>>(fwd, rev, W, bias, len, out);
}

// Round 2
// 209.727 us; speedup vs baseline: 1.5123x; 1.5123x over previous
//
#include <hip/hip_runtime.h>
#include <hip/hip_bf16.h>
#include <stdint.h>

// Problem constants
#define B_   8
#define S_   2048
#define D_   1280
#define OUT_ 1280
#define K_   (2 * D_)     // 2560
#define M_   (B_ * S_)    // 16384

#define BM 128
#define BN 128
#define BK 32
#define NKT (K_ / BK)     // 80 K-tiles
#define TILE_E (BM * BK)  // 4096 bf16 elems = 8192 bytes per tile

typedef __bf16 bf16_t;
typedef bf16_t bf16x8 __attribute__((ext_vector_type(8)));
typedef float  f32x4  __attribute__((ext_vector_type(4)));

// ---------------------------------------------------------------------------
// lengths: per-batch valid count (prefix mask). Handles byte or int32 storage.
// ---------------------------------------------------------------------------
__global__ void lengths_kernel(const unsigned char* __restrict__ mask,
                               int* __restrict__ len) {
    const int b = blockIdx.x;
    const bool bytefmt = (mask[1] != 0);   // lengths >= 512 so elem 1 is true
    int cnt = 0;
    if (bytefmt) {
        for (int s = threadIdx.x; s < S_; s += blockDim.x)
            cnt += (mask[(size_t)b * S_ + s] != 0) ? 1 : 0;
    } else {
        const int* mi = (const int*)mask;
        for (int s = threadIdx.x; s < S_; s += blockDim.x)
            cnt += (mi[(size_t)b * S_ + s] != 0) ? 1 : 0;
    }
    #pragma unroll
    for (int off = 32; off > 0; off >>= 1) cnt += __shfl_down(cnt, off);
    __shared__ int wsum[4];
    const int wid = threadIdx.x >> 6;
    if ((threadIdx.x & 63) == 0) wsum[wid] = cnt;
    __syncthreads();
    if (threadIdx.x == 0) len[b] = wsum[0] + wsum[1] + wsum[2] + wsum[3];
}

__device__ inline bf16x8 cvt8(float4 x, float4 y) {
    bf16x8 r;
    r[0] = (bf16_t)x.x; r[1] = (bf16_t)x.y; r[2] = (bf16_t)x.z; r[3] = (bf16_t)x.w;
    r[4] = (bf16_t)y.x; r[5] = (bf16_t)y.y; r[6] = (bf16_t)y.z; r[7] = (bf16_t)y.w;
    return r;
}

// ---------------------------------------------------------------------------
// Pack A: f32 -> bf16, fused masked-reverse gather, tiled+swizzled layout.
// packA[mt][kt] is an 8192-byte tile; within: chunk c (8 bf16, k=c*8..c*8+7)
// of row r stored at slot (c ^ ((r>>1)&3)), elem offset r*32 + slot*8.
// Block = one (mt,kt) tile, 256 threads x 2 chunks. Reads 64B-coalesced/row,
// writes fully linear.
// ---------------------------------------------------------------------------
__global__ __launch_bounds__(256) void pack_a_kernel(
    const float* __restrict__ fwd, const float* __restrict__ rev,
    const int* __restrict__ len, bf16_t* __restrict__ packA) {
    const int kt = blockIdx.x;            // 0..79
    const int mt = blockIdx.y;            // 0..127
    const int b  = mt >> 4;               // 16 m-tiles per batch
    const int n  = len[b];
    bf16_t* dst = packA + ((size_t)mt * NKT + kt) * TILE_E;
    #pragma unroll
    for (int p = 0; p < 2; ++p) {
        const int idx16 = p * 256 + threadIdx.x;   // 0..511
        const int row  = idx16 >> 2;
        const int slot = idx16 & 3;
        const int c    = slot ^ ((row >> 1) & 3);
        const int k0   = kt * BK + c * 8;
        const int m    = mt * BM + row;
        const int s    = m & (S_ - 1);
        const float* src;
        if (k0 < D_) {
            src = fwd + ((size_t)(b * S_ + s)) * D_ + k0;
        } else {
            const int ss = (s < n) ? (n - 1 - s) : s;
            src = rev + ((size_t)(b * S_ + ss)) * D_ + (k0 - D_);
        }
        float4 x = *(const float4*)(src);
        float4 y = *(const float4*)(src + 4);
        *(bf16x8*)(dst + (size_t)idx16 * 8) = cvt8(x, y);
    }
}

// Pack W: same layout, no gather. packW[nt][kt] tiles.
__global__ __launch_bounds__(256) void pack_w_kernel(
    const float* __restrict__ W, bf16_t* __restrict__ packW) {
    const int kt = blockIdx.x;            // 0..79
    const int nt = blockIdx.y;            // 0..9
    bf16_t* dst = packW + ((size_t)nt * NKT + kt) * TILE_E;
    #pragma unroll
    for (int p = 0; p < 2; ++p) {
        const int idx16 = p * 256 + threadIdx.x;
        const int row  = idx16 >> 2;
        const int slot = idx16 & 3;
        const int c    = slot ^ ((row >> 1) & 3);
        const int k0   = kt * BK + c * 8;
        const float* src = W + ((size_t)(nt * BN + row)) * K_ + k0;
        float4 x = *(const float4*)(src);
        float4 y = *(const float4*)(src + 4);
        *(bf16x8*)(dst + (size_t)idx16 * 8) = cvt8(x, y);
    }
}

// ---------------------------------------------------------------------------
// GEMM on packed bf16 tiles. 128x128 tile, BK=32, 4 waves (2x2 of 64x64),
// double-buffered LDS staged via global_load_lds (16B/lane, linear), swizzled
// ds_read_b128 fragments (2-way bank aliasing = free).
// ---------------------------------------------------------------------------
#define GLL(gp, lp) __builtin_amdgcn_global_load_lds(                        \
    (const __attribute__((address_space(1))) unsigned int*)(const void*)(gp),\
    (__attribute__((address_space(3))) unsigned int*)(void*)(lp), 16, 0, 0)

__global__ __launch_bounds__(256) void gemm_packed_kernel(
    const bf16_t* __restrict__ pA, const bf16_t* __restrict__ pW,
    const float* __restrict__ bias, float* __restrict__ out) {

    __shared__ __align__(16) bf16_t lds_a[2][TILE_E];
    __shared__ __align__(16) bf16_t lds_b[2][TILE_E];

    const int ct = blockIdx.x;            // 0..9
    const int rt = blockIdx.y;            // 0..127
    const int t  = threadIdx.x;
    const int l  = t & 63;
    const int w  = t >> 6;
    const int wr = w >> 1, wc = w & 1;

    const bf16_t* gA = pA + (size_t)rt * NKT * TILE_E;
    const bf16_t* gB = pW + (size_t)ct * NKT * TILE_E;

    // staging: wave w covers elems [w*1024, w*1024+1024) of each tile in two
    // 512-elem (1KB) calls; lane adds l*8 elems (16B).
    const int se0 = w * 1024 + l * 8;     // global per-lane elem offset, call 0
    const int sl0 = w * 1024;             // LDS wave-uniform base, call 0

    f32x4 acc[4][4] = {};

    // prologue: stage tile 0 into buf 0
    {
        const bf16_t* a = gA;
        const bf16_t* b = gB;
        GLL(a + se0,       &lds_a[0][sl0]);
        GLL(a + se0 + 512, &lds_a[0][sl0 + 512]);
        GLL(b + se0,       &lds_b[0][sl0]);
        GLL(b + se0 + 512, &lds_b[0][sl0 + 512]);
    }
    __syncthreads();

    const int lrow = l & 15;
    const int c    = l >> 4;              // k-chunk id for this lane

    int cur = 0;
    for (int kt = 0; kt < NKT; ++kt) {
        if (kt + 1 < NKT) {
            const bf16_t* a = gA + (size_t)(kt + 1) * TILE_E;
            const bf16_t* b = gB + (size_t)(kt + 1) * TILE_E;
            const int nxt = cur ^ 1;
            GLL(a + se0,       &lds_a[nxt][sl0]);
            GLL(a + se0 + 512, &lds_a[nxt][sl0 + 512]);
            GLL(b + se0,       &lds_b[nxt][sl0]);
            GLL(b + se0 + 512, &lds_b[nxt][sl0 + 512]);
        }

        bf16x8 af[4], bfr[4];
        #pragma unroll
        for (int i = 0; i < 4; ++i) {
            const int row = wr * 64 + i * 16 + lrow;
            const int off = row * 32 + ((c ^ ((row >> 1) & 3)) * 8);
            af[i] = *(const bf16x8*)&lds_a[cur][off];
        }
        #pragma unroll
        for (int j = 0; j < 4; ++j) {
            const int row = wc * 64 + j * 16 + lrow;
            const int off = row * 32 + ((c ^ ((row >> 1) & 3)) * 8);
            bfr[j] = *(const bf16x8*)&lds_b[cur][off];
        }

        #pragma unroll
        for (int i = 0; i < 4; ++i)
            #pragma unroll
            for (int j = 0; j < 4; ++j)
                acc[i][j] = __builtin_amdgcn_mfma_f32_16x16x32_bf16(
                    af[i], bfr[j], acc[i][j], 0, 0, 0);

        __syncthreads();   // drains vmcnt(0): next buffer fully staged
        cur ^= 1;
    }

    // epilogue: C/D layout col=lane&15, row=(lane>>4)*4+v
    const int m0 = rt * BM, n0 = ct * BN;
    #pragma unroll
    for (int j = 0; j < 4; ++j) {
        const int col = n0 + wc * 64 + j * 16 + lrow;
        const float bj = bias[col];
        #pragma unroll
        for (int i = 0; i < 4; ++i) {
            const int row0 = m0 + wr * 64 + i * 16 + (l >> 4) * 4;
            #pragma unroll
            for (int v = 0; v < 4; ++v)
                out[(size_t)(row0 + v) * OUT_ + col] = acc[i][j][v] + bj;
        }
    }
}

// ---------------------------------------------------------------------------
// Fallback (round-1 kernel): used only if ws_size can't hold packed operands.
// ---------------------------------------------------------------------------
#define LDKF 40
__global__ __launch_bounds__(256) void profam_gemm_fallback(
    const float* __restrict__ fwd, const float* __restrict__ rev,
    const float* __restrict__ W,   const float* __restrict__ bias,
    const int* __restrict__ len,   float* __restrict__ out) {

    __shared__ __align__(16) bf16_t lds_a[BM][LDKF];
    __shared__ __align__(16) bf16_t lds_b[BN][LDKF];

    const int ct = blockIdx.x;
    const int rt = blockIdx.y;
    const int m0 = rt * BM;
    const int n0 = ct * BN;
    const int t  = threadIdx.x;
    const int l  = t & 63;
    const int w  = t >> 6;
    const int wr = w >> 1, wc = w & 1;

    const int b = m0 >> 11;
    const int n = len[b];

    const int sr = t >> 1;
    const int cg = (t & 1) * 16;
    const int s  = (m0 + sr) & (S_ - 1);
    const int ss = (s < n) ? (n - 1 - s) : s;
    const float* pf = fwd + (size_t)(b * S_ + s)  * D_ + cg;
    const float* pr = rev + (size_t)(b * S_ + ss) * D_ + cg;
    const float* pw = W   + (size_t)(n0 + sr) * K_ + cg;

    f32x4 acc[4][4] = {};
    const int lrow = l & 15;
    const int kc   = (l >> 4) * 8;

    for (int kt = 0; kt < K_ / BK; ++kt) {
        const int k0 = kt * BK;
        const float* pa = (k0 < D_) ? (pf + k0) : (pr + (k0 - D_));
        const float* pb = pw + k0;
        float4 a0 = *(const float4*)(pa + 0);
        float4 a1 = *(const float4*)(pa + 4);
        float4 a2 = *(const float4*)(pa + 8);
        float4 a3 = *(const float4*)(pa + 12);
        float4 b0 = *(const float4*)(pb + 0);
        float4 b1 = *(const float4*)(pb + 4);
        float4 b2 = *(const float4*)(pb + 8);
        float4 b3 = *(const float4*)(pb + 12);
        *(bf16x8*)&lds_a[sr][cg + 0] = cvt8(a0, a1);
        *(bf16x8*)&lds_a[sr][cg + 8] = cvt8(a2, a3);
        *(bf16x8*)&lds_b[sr][cg + 0] = cvt8(b0, b1);
        *(bf16x8*)&lds_b[sr][cg + 8] = cvt8(b2, b3);
        __syncthreads();
        bf16x8 af[4], bfr[4];
        #pragma unroll
        for (int i = 0; i < 4; ++i)
            af[i] = *(const bf16x8*)&lds_a[wr * 64 + i * 16 + lrow][kc];
        #pragma unroll
        for (int j = 0; j < 4; ++j)
            bfr[j] = *(const bf16x8*)&lds_b[wc * 64 + j * 16 + lrow][kc];
        #pragma unroll
        for (int i = 0; i < 4; ++i)
            #pragma unroll
            for (int j = 0; j < 4; ++j)
                acc[i][j] = __builtin_amdgcn_mfma_f32_16x16x32_bf16(
                    af[i], bfr[j], acc[i][j], 0, 0, 0);
        __syncthreads();
    }
    #pragma unroll
    for (int j = 0; j < 4; ++j) {
        const int col = n0 + wc * 64 + j * 16 + lrow;
        const float bj = bias[col];
        #pragma unroll
        for (int i = 0; i < 4; ++i) {
            const int row0 = m0 + wr * 64 + i * 16 + (l >> 4) * 4;
            #pragma unroll
            for (int v = 0; v < 4; ++v)
                out[(size_t)(row0 + v) * OUT_ + col] = acc[i][j][v] + bj;
        }
    }
}

extern "C" void kernel_launch(void* const* d_in, const int* in_sizes, int n_in,
                              void* d_out, int out_size, void* d_ws, size_t ws_size,
                              hipStream_t stream) {
    const float* fwd  = (const float*)d_in[0];
    const float* rev  = (const float*)d_in[1];
    const unsigned char* mask = (const unsigned char*)d_in[2];
    const float* W    = (const float*)d_in[3];
    const float* bias = (const float*)d_in[4];
    float* out = (float*)d_out;

    int* len = (int*)d_ws;                                   // 8 ints @ offset 0
    const size_t offA = 256;
    const size_t szA  = (size_t)128 * NKT * TILE_E * 2;      // 83.89 MB
    const size_t offW = offA + szA;
    const size_t szW  = (size_t)10 * NKT * TILE_E * 2;       // 6.55 MB
    const size_t need = offW + szW;

    lengths_kernel<<<dim3(B_), dim3(256), 0, stream>>>(mask, len);

    if (ws_size >= need) {
        bf16_t* packA = (bf16_t*)((char*)d_ws + offA);
        bf16_t* packW = (bf16_t*)((char*)d_ws + offW);
        pack_a_kernel<<<dim3(NKT, M_ / BM), dim3(256), 0, stream>>>(fwd, rev, len, packA);
        pack_w_kernel<<<dim3(NKT, OUT_ / BN), dim3(256), 0, stream>>>(W, packW);
        gemm_packed_kernel<<<dim3(OUT_ / BN, M_ / BM), dim3(256), 0, stream>>>(
            packA, packW, bias, out);
    } else {
        profam_gemm_fallback<<<dim3(OUT_ / BN, M_ / BM), dim3(256), 0, stream>>>(
            fwd, rev, W, bias, len, out);
    }
}

// Round 3
// 178.080 us; speedup vs baseline: 1.7811x; 1.1777x over previous
//
#include <hip/hip_runtime.h>
#include <hip/hip_bf16.h>
#include <stdint.h>

// Problem constants
#define B_   8
#define S_   2048
#define D_   1280
#define OUT_ 1280
#define K_   (2 * D_)     // 2560
#define M_   (B_ * S_)    // 16384

// GEMM geometry (8-phase-class schedule)
#define BM   256
#define BN   128
#define BKT  64
#define NKT  (K_ / BKT)       // 40 K-tiles
#define AT_E (BM * BKT)       // 16384 elems per A K-tile (32 KB)
#define BT_E (BN * BKT)       // 8192  elems per B K-tile (16 KB)
#define NMT  (M_ / BM)        // 64
#define NNT  (OUT_ / BN)      // 10
#define BUF_E (AT_E + BT_E)   // 24576 elems per LDS buffer (48 KB)

typedef __bf16 bf16_t;
typedef bf16_t bf16x8 __attribute__((ext_vector_type(8)));
typedef float  f32x4  __attribute__((ext_vector_type(4)));

// ---------------------------------------------------------------------------
// lengths: per-batch valid count (prefix mask). Handles byte or int32 storage.
// ---------------------------------------------------------------------------
__global__ void lengths_kernel(const unsigned char* __restrict__ mask,
                               int* __restrict__ len) {
    const int b = blockIdx.x;
    const bool bytefmt = (mask[1] != 0);   // lengths >= 512 so elem 1 is true
    int cnt = 0;
    if (bytefmt) {
        for (int s = threadIdx.x; s < S_; s += blockDim.x)
            cnt += (mask[(size_t)b * S_ + s] != 0) ? 1 : 0;
    } else {
        const int* mi = (const int*)mask;
        for (int s = threadIdx.x; s < S_; s += blockDim.x)
            cnt += (mi[(size_t)b * S_ + s] != 0) ? 1 : 0;
    }
    #pragma unroll
    for (int off = 32; off > 0; off >>= 1) cnt += __shfl_down(cnt, off);
    __shared__ int wsum[4];
    const int wid = threadIdx.x >> 6;
    if ((threadIdx.x & 63) == 0) wsum[wid] = cnt;
    __syncthreads();
    if (threadIdx.x == 0) len[b] = wsum[0] + wsum[1] + wsum[2] + wsum[3];
}

__device__ inline bf16x8 cvt8(float4 x, float4 y) {
    bf16x8 r;
    r[0] = (bf16_t)x.x; r[1] = (bf16_t)x.y; r[2] = (bf16_t)x.z; r[3] = (bf16_t)x.w;
    r[4] = (bf16_t)y.x; r[5] = (bf16_t)y.y; r[6] = (bf16_t)y.z; r[7] = (bf16_t)y.w;
    return r;
}

// ---------------------------------------------------------------------------
// Pack A: f32 -> bf16, fused masked-reverse gather, [64 mt][40 kt][256x64]
// tiles. Within a tile, 16B chunk c8 (k = c8*8..+8) of row r stored at slot
// (c8 ^ (r&7)): elem offset r*64 + slot*8. Linear gload_lds staging +
// conflict-free swizzled ds_read both fall out of this (rule 21: source
// permutation == read permutation, LDS dest linear).
// ---------------------------------------------------------------------------
__global__ __launch_bounds__(256) void pack_a2_kernel(
    const float* __restrict__ fwd, const float* __restrict__ rev,
    const int* __restrict__ len, bf16_t* __restrict__ packA) {
    const int kt = blockIdx.x;            // 0..39
    const int mt = blockIdx.y;            // 0..63
    const int b  = mt >> 3;               // 8 m-tiles (256 rows) per batch
    const int n  = len[b];
    bf16_t* dst = packA + ((size_t)mt * NKT + kt) * AT_E;
    const int c8 = threadIdx.x & 7;
    const int r0 = threadIdx.x >> 3;      // 0..31
    const int kk = kt * BKT + c8 * 8;     // global k
    const int slot = c8 ^ (r0 & 7);       // (r&7)==(r0&7) since rows step by 32
    #pragma unroll
    for (int p = 0; p < 8; ++p) {
        const int r = r0 + p * 32;
        const int s = ((mt & 7) * 256 + r);
        const float* src;
        if (kk < D_) {
            src = fwd + (size_t)(b * S_ + s) * D_ + kk;
        } else {
            const int ss = (s < n) ? (n - 1 - s) : s;
            src = rev + (size_t)(b * S_ + ss) * D_ + (kk - D_);
        }
        float4 x = *(const float4*)src;
        float4 y = *(const float4*)(src + 4);
        *(bf16x8*)(dst + r * 64 + slot * 8) = cvt8(x, y);
    }
}

// Pack W: same layout, [10 nt][40 kt][128x64] tiles.
__global__ __launch_bounds__(256) void pack_w2_kernel(
    const float* __restrict__ W, bf16_t* __restrict__ packW) {
    const int kt = blockIdx.x;            // 0..39
    const int nt = blockIdx.y;            // 0..9
    bf16_t* dst = packW + ((size_t)nt * NKT + kt) * BT_E;
    const int c8 = threadIdx.x & 7;
    const int r0 = threadIdx.x >> 3;
    const int kk = kt * BKT + c8 * 8;
    const int slot = c8 ^ (r0 & 7);
    #pragma unroll
    for (int p = 0; p < 4; ++p) {
        const int r = r0 + p * 32;
        const float* src = W + (size_t)(nt * BN + r) * K_ + kk;
        float4 x = *(const float4*)src;
        float4 y = *(const float4*)(src + 4);
        *(bf16x8*)(dst + r * 64 + slot * 8) = cvt8(x, y);
    }
}

// ---------------------------------------------------------------------------
// GEMM, deep-pipelined: 256x128 tile, BK=64, 8 waves (4Mx2N, 64x64 each),
// 3-deep LDS buffers, global_load_lds staging of tile t+2 during compute of
// tile t, counted vmcnt(6), raw barriers, setprio around MFMA clusters.
// ---------------------------------------------------------------------------
#define GLL(gp, lp) __builtin_amdgcn_global_load_lds(                        \
    (const __attribute__((address_space(1))) unsigned int*)(const void*)(gp),\
    (__attribute__((address_space(3))) unsigned int*)(void*)(lp), 16, 0, 0)

__global__ __launch_bounds__(512) void gemm8p_kernel(
    const bf16_t* __restrict__ pA, const bf16_t* __restrict__ pW,
    const float* __restrict__ bias, float* __restrict__ out) {

    __shared__ __align__(16) bf16_t lds[3 * BUF_E];   // 144 KB

    // XCD-bijective swizzle: 640 blocks = 8 XCDs x 80; XCD k gets rt in [8k,8k+8)
    const int bid = blockIdx.x;
    const int swz = (bid & 7) * 80 + (bid >> 3);
    const int ct  = swz % NNT;            // 0..9
    const int rt  = swz / NNT;            // 0..63

    const int t  = threadIdx.x;
    const int l  = t & 63;
    const int w  = t >> 6;                // 0..7
    const int wm = w >> 1;                // 0..3  (64-row group)
    const int wn = w & 1;                 // 0..1  (64-col group)

    const bf16_t* gA = pA + (size_t)rt * NKT * AT_E;
    const bf16_t* gB = pW + (size_t)ct * NKT * BT_E;

    const int stl  = w * 512 + l * 8;     // per-lane elem offset within a 4096-elem unit
    const int wofs = w * 512;             // wave-uniform LDS part of same

    // fragment per-lane offsets (elems): row r = wm*64 + i*16 + (l&15),
    // chunk c8 = c*4 + (l>>4), slot = c8 ^ (r&7), (r&7) == (l&7).
    const int lrow = l & 15;
    const int s0   = (l >> 4) ^ (l & 7);  // slot for c=0
    const int aoff0 = (wm * 64 + lrow) * 64 + s0 * 8;
    const int aoff1 = (wm * 64 + lrow) * 64 + (s0 ^ 4) * 8;
    const int boff0 = AT_E + (wn * 64 + lrow) * 64 + s0 * 8;
    const int boff1 = AT_E + (wn * 64 + lrow) * 64 + (s0 ^ 4) * 8;

    f32x4 acc[4][4] = {};

    // ---- prologue: stage tiles 0 (buf0) and 1 (buf1); 12 loads in flight ----
    {
        const bf16_t* a = gA;
        const bf16_t* b = gB;
        #pragma unroll
        for (int u = 0; u < 4; ++u) GLL(a + u * 4096 + stl, &lds[u * 4096 + wofs]);
        #pragma unroll
        for (int u = 0; u < 2; ++u) GLL(b + u * 4096 + stl, &lds[AT_E + u * 4096 + wofs]);
        a = gA + AT_E;
        b = gB + BT_E;
        #pragma unroll
        for (int u = 0; u < 4; ++u) GLL(a + u * 4096 + stl, &lds[BUF_E + u * 4096 + wofs]);
        #pragma unroll
        for (int u = 0; u < 2; ++u) GLL(b + u * 4096 + stl, &lds[BUF_E + AT_E + u * 4096 + wofs]);
    }

    int o0 = 0, o1 = BUF_E, o2 = 2 * BUF_E;   // compute / next / stage-target buffers

    for (int kt = 0; kt < NKT; ++kt) {
        // tile boundary: previous tile's stages landed (counted, never 0 in-loop)
        if (kt + 1 < NKT) asm volatile("s_waitcnt vmcnt(6)" ::: "memory");
        else              asm volatile("s_waitcnt vmcnt(0)" ::: "memory");
        __builtin_amdgcn_s_barrier();
        __builtin_amdgcn_sched_barrier(0);

        const bf16_t* sa = gA + (size_t)(kt + 2) * AT_E;
        const bf16_t* sb = gB + (size_t)(kt + 2) * BT_E;
        const bool st = (kt + 2 < NKT);

        // ---------------- phase 0 (k-chunk c = 0) ----------------
        {
            bf16x8 af[4], bfr[4];
            #pragma unroll
            for (int i = 0; i < 4; ++i)
                af[i] = *(const bf16x8*)&lds[o0 + aoff0 + i * 1024];
            #pragma unroll
            for (int j = 0; j < 4; ++j)
                bfr[j] = *(const bf16x8*)&lds[o0 + boff0 + j * 1024];

            if (st) {
                GLL(sa + 0 * 4096 + stl, &lds[o2 + 0 * 4096 + wofs]);
                GLL(sa + 1 * 4096 + stl, &lds[o2 + 1 * 4096 + wofs]);
                GLL(sb + 0 * 4096 + stl, &lds[o2 + AT_E + 0 * 4096 + wofs]);
            }

            __builtin_amdgcn_s_setprio(1);
            #pragma unroll
            for (int i = 0; i < 4; ++i)
                #pragma unroll
                for (int j = 0; j < 4; ++j)
                    acc[i][j] = __builtin_amdgcn_mfma_f32_16x16x32_bf16(
                        af[i], bfr[j], acc[i][j], 0, 0, 0);
            __builtin_amdgcn_s_setprio(0);
        }
        __builtin_amdgcn_s_barrier();        // mid-tile lockstep
        __builtin_amdgcn_sched_barrier(0);

        // ---------------- phase 1 (k-chunk c = 1) ----------------
        {
            bf16x8 af[4], bfr[4];
            #pragma unroll
            for (int i = 0; i < 4; ++i)
                af[i] = *(const bf16x8*)&lds[o0 + aoff1 + i * 1024];
            #pragma unroll
            for (int j = 0; j < 4; ++j)
                bfr[j] = *(const bf16x8*)&lds[o0 + boff1 + j * 1024];

            if (st) {
                GLL(sa + 2 * 4096 + stl, &lds[o2 + 2 * 4096 + wofs]);
                GLL(sa + 3 * 4096 + stl, &lds[o2 + 3 * 4096 + wofs]);
                GLL(sb + 1 * 4096 + stl, &lds[o2 + AT_E + 1 * 4096 + wofs]);
            }

            __builtin_amdgcn_s_setprio(1);
            #pragma unroll
            for (int i = 0; i < 4; ++i)
                #pragma unroll
                for (int j = 0; j < 4; ++j)
                    acc[i][j] = __builtin_amdgcn_mfma_f32_16x16x32_bf16(
                        af[i], bfr[j], acc[i][j], 0, 0, 0);
            __builtin_amdgcn_s_setprio(0);
        }

        // rotate buffers: (compute, next, stage) <- (next, stage, compute)
        const int tmp = o0; o0 = o1; o1 = o2; o2 = tmp;
    }

    // ---- epilogue: C/D layout col=lane&15, row=(lane>>4)*4+v ----
    const int m0 = rt * BM + wm * 64;
    const int n0 = ct * BN + wn * 64;
    const int r4 = (l >> 4) * 4;
    #pragma unroll
    for (int j = 0; j < 4; ++j) {
        const int col = n0 + j * 16 + lrow;
        const float bj = bias[col];
        #pragma unroll
        for (int i = 0; i < 4; ++i) {
            const int row0 = m0 + i * 16 + r4;
            #pragma unroll
            for (int v = 0; v < 4; ++v)
                out[(size_t)(row0 + v) * OUT_ + col] = acc[i][j][v] + bj;
        }
    }
}

// ---------------------------------------------------------------------------
// Fallback (round-1 kernel): used only if ws_size can't hold packed operands.
// ---------------------------------------------------------------------------
#define LDKF 40
__global__ __launch_bounds__(256) void profam_gemm_fallback(
    const float* __restrict__ fwd, const float* __restrict__ rev,
    const float* __restrict__ W,   const float* __restrict__ bias,
    const int* __restrict__ len,   float* __restrict__ out) {

    __shared__ __align__(16) bf16_t lds_a[128][LDKF];
    __shared__ __align__(16) bf16_t lds_b[128][LDKF];

    const int ct = blockIdx.x;
    const int rt = blockIdx.y;
    const int m0 = rt * 128;
    const int n0 = ct * 128;
    const int t  = threadIdx.x;
    const int l  = t & 63;
    const int w  = t >> 6;
    const int wr = w >> 1, wc = w & 1;

    const int b = m0 >> 11;
    const int n = len[b];

    const int sr = t >> 1;
    const int cg = (t & 1) * 16;
    const int s  = (m0 + sr) & (S_ - 1);
    const int ss = (s < n) ? (n - 1 - s) : s;
    const float* pf = fwd + (size_t)(b * S_ + s)  * D_ + cg;
    const float* pr = rev + (size_t)(b * S_ + ss) * D_ + cg;
    const float* pw = W   + (size_t)(n0 + sr) * K_ + cg;

    f32x4 acc[4][4] = {};
    const int lrow = l & 15;
    const int kc   = (l >> 4) * 8;

    for (int kt = 0; kt < K_ / 32; ++kt) {
        const int k0 = kt * 32;
        const float* pa = (k0 < D_) ? (pf + k0) : (pr + (k0 - D_));
        const float* pb = pw + k0;
        float4 a0 = *(const float4*)(pa + 0);
        float4 a1 = *(const float4*)(pa + 4);
        float4 a2 = *(const float4*)(pa + 8);
        float4 a3 = *(const float4*)(pa + 12);
        float4 b0 = *(const float4*)(pb + 0);
        float4 b1 = *(const float4*)(pb + 4);
        float4 b2 = *(const float4*)(pb + 8);
        float4 b3 = *(const float4*)(pb + 12);
        *(bf16x8*)&lds_a[sr][cg + 0] = cvt8(a0, a1);
        *(bf16x8*)&lds_a[sr][cg + 8] = cvt8(a2, a3);
        *(bf16x8*)&lds_b[sr][cg + 0] = cvt8(b0, b1);
        *(bf16x8*)&lds_b[sr][cg + 8] = cvt8(b2, b3);
        __syncthreads();
        bf16x8 af[4], bfr[4];
        #pragma unroll
        for (int i = 0; i < 4; ++i)
            af[i] = *(const bf16x8*)&lds_a[wr * 64 + i * 16 + lrow][kc];
        #pragma unroll
        for (int j = 0; j < 4; ++j)
            bfr[j] = *(const bf16x8*)&lds_b[wc * 64 + j * 16 + lrow][kc];
        #pragma unroll
        for (int i = 0; i < 4; ++i)
            #pragma unroll
            for (int j = 0; j < 4; ++j)
                acc[i][j] = __builtin_amdgcn_mfma_f32_16x16x32_bf16(
                    af[i], bfr[j], acc[i][j], 0, 0, 0);
        __syncthreads();
    }
    #pragma unroll
    for (int j = 0; j < 4; ++j) {
        const int col = n0 + wc * 64 + j * 16 + lrow;
        const float bj = bias[col];
        #pragma unroll
        for (int i = 0; i < 4; ++i) {
            const int row0 = m0 + wr * 64 + i * 16 + (l >> 4) * 4;
            #pragma unroll
            for (int v = 0; v < 4; ++v)
                out[(size_t)(row0 + v) * OUT_ + col] = acc[i][j][v] + bj;
        }
    }
}

extern "C" void kernel_launch(void* const* d_in, const int* in_sizes, int n_in,
                              void* d_out, int out_size, void* d_ws, size_t ws_size,
                              hipStream_t stream) {
    const float* fwd  = (const float*)d_in[0];
    const float* rev  = (const float*)d_in[1];
    const unsigned char* mask = (const unsigned char*)d_in[2];
    const float* W    = (const float*)d_in[3];
    const float* bias = (const float*)d_in[4];
    float* out = (float*)d_out;

    int* len = (int*)d_ws;                                    // 8 ints @ offset 0
    const size_t offA = 256;
    const size_t szA  = (size_t)NMT * NKT * AT_E * 2;         // 83.89 MB
    const size_t offW = offA + szA;
    const size_t szW  = (size_t)NNT * NKT * BT_E * 2;         // 6.55 MB
    const size_t need = offW + szW;

    lengths_kernel<<<dim3(B_), dim3(256), 0, stream>>>(mask, len);

    if (ws_size >= need) {
        bf16_t* packA = (bf16_t*)((char*)d_ws + offA);
        bf16_t* packW = (bf16_t*)((char*)d_ws + offW);
        pack_a2_kernel<<<dim3(NKT, NMT), dim3(256), 0, stream>>>(fwd, rev, len, packA);
        pack_w2_kernel<<<dim3(NKT, NNT), dim3(256), 0, stream>>>(W, packW);
        gemm8p_kernel<<<dim3(NNT * NMT), dim3(512), 0, stream>>>(packA, packW, bias, out);
    } else {
        profam_gemm_fallback<<<dim3(OUT_ / 128, M_ / 128), dim3(256), 0, stream>>>(
            fwd, rev, W, bias, len, out);
    }
}